// Round 7
// baseline (7040.955 us; speedup 1.0000x reference)
//
#include <hip/hip_runtime.h>
#include <cstdint>
#include <cstddef>

#define T_ 512
#define B_ 64
#define I_ 512
#define H_ 512
#define SENT32 0x7FC07FC0

typedef __attribute__((ext_vector_type(8))) short short8;
typedef __attribute__((ext_vector_type(4))) float f32x4;
typedef __attribute__((ext_vector_type(4))) int i32x4;

#define MFMA(a, b, c) __builtin_amdgcn_mfma_f32_16x16x32_bf16((a), (b), (c), 0, 0, 0)

__device__ __forceinline__ unsigned short f2bf(float f) {
  union { float f; unsigned u; } v; v.f = f;
  unsigned r = v.u + 0x7fffu + ((v.u >> 16) & 1u);
  return (unsigned short)(r >> 16);
}

__device__ __forceinline__ float sigm(float x) { return 1.0f / (1.0f + __expf(-x)); }
__device__ __forceinline__ float tanh_fast(float x) {
  float e = __expf(2.0f * x);
  return 1.0f - 2.0f / (e + 1.0f);
}

__device__ __forceinline__ short8 loadWfrag(const float* __restrict__ p) {
  float4 a = ((const float4*)p)[0];
  float4 b = ((const float4*)p)[1];
  short8 r;
  r[0] = (short)f2bf(a.x); r[1] = (short)f2bf(a.y);
  r[2] = (short)f2bf(a.z); r[3] = (short)f2bf(a.w);
  r[4] = (short)f2bf(b.x); r[5] = (short)f2bf(b.y);
  r[6] = (short)f2bf(b.z); r[7] = (short)f2bf(b.w);
  return r;
}

// 16B store, LLC-visible (write-through past L1+L2)
__device__ __forceinline__ void st16(void* p, i32x4 v) {
  asm volatile("global_store_dwordx4 %0, %1, off sc0 sc1" :: "v"(p), "v"(v) : "memory");
}

// h chunk full loads: dwordx4 at 64B stride, LLC scope (bypass stale L1/L2)
#define LDH1(i, OFF)                                                          \
  asm volatile("global_load_dwordx4 %0, %1, off offset:" OFF " sc0 sc1"       \
               : "=v"(hf[i]) : "v"(hsrc) : "memory")
#define LDH_ALL()                                                             \
  LDH1(0, "0"); LDH1(1, "64"); LDH1(2, "128"); LDH1(3, "192");                \
  LDH1(4, "256"); LDH1(5, "320"); LDH1(6, "384"); LDH1(7, "448");             \
  LDH1(8, "512"); LDH1(9, "576"); LDH1(10, "640"); LDH1(11, "704");           \
  LDH1(12, "768"); LDH1(13, "832"); LDH1(14, "896"); LDH1(15, "960")
// masked full loads
#define LDH_IFM(i, OFF, M) if (((M) >> i) & 1u) { LDH1(i, OFF); }
#define LDH_MASK(M)                                                           \
  LDH_IFM(0, "0", M) LDH_IFM(1, "64", M) LDH_IFM(2, "128", M)                 \
  LDH_IFM(3, "192", M) LDH_IFM(4, "256", M) LDH_IFM(5, "320", M)              \
  LDH_IFM(6, "384", M) LDH_IFM(7, "448", M) LDH_IFM(8, "512", M)              \
  LDH_IFM(9, "576", M) LDH_IFM(10, "640", M) LDH_IFM(11, "704", M)            \
  LDH_IFM(12, "768", M) LDH_IFM(13, "832", M) LDH_IFM(14, "896", M)           \
  LDH_IFM(15, "960", M)
// 4B probes (dword0 of the chunk): 1/4 the NoC transfer of a full reload
#define PRB1(i, OFF)                                                          \
  asm volatile("global_load_dword %0, %1, off offset:" OFF " sc0 sc1"         \
               : "=v"(pr[i]) : "v"(hsrc) : "memory")
#define PRB_IFM(i, OFF, M) if (((M) >> i) & 1u) { PRB1(i, OFF); }
#define PRB_MASK(M)                                                           \
  PRB_IFM(0, "0", M) PRB_IFM(1, "64", M) PRB_IFM(2, "128", M)                 \
  PRB_IFM(3, "192", M) PRB_IFM(4, "256", M) PRB_IFM(5, "320", M)              \
  PRB_IFM(6, "384", M) PRB_IFM(7, "448", M) PRB_IFM(8, "512", M)              \
  PRB_IFM(9, "576", M) PRB_IFM(10, "640", M) PRB_IFM(11, "704", M)            \
  PRB_IFM(12, "768", M) PRB_IFM(13, "832", M) PRB_IFM(14, "896", M)           \
  PRB_IFM(15, "960", M)
// consume chunks in mask M (2 MFMAs each)
#define CONSUME(M)                                                            \
  _Pragma("unroll")                                                           \
  for (int kk = 0; kk < 16; ++kk)                                             \
    if (((M) >> kk) & 1u) {                                                   \
      acc0 = MFMA(hf[kk], wh[0][kk], acc0);                                   \
      acc1 = MFMA(hf[kk], wh[1][kk], acc1);                                   \
    }

#define LDX1(i, OFF)                                                          \
  asm volatile("global_load_dwordx4 %0, %1, off offset:" OFF                  \
               : "=v"(xf[i]) : "v"(xsrc) : "memory")
#define LDX_ALL()                                                             \
  LDX1(0, "0"); LDX1(1, "64"); LDX1(2, "128"); LDX1(3, "192");                \
  LDX1(4, "256"); LDX1(5, "320"); LDX1(6, "384"); LDX1(7, "448");             \
  LDX1(8, "512"); LDX1(9, "576"); LDX1(10, "640"); LDX1(11, "704");           \
  LDX1(12, "768"); LDX1(13, "832"); LDX1(14, "896"); LDX1(15, "960")

// ---- prep: convert X (T,B,I) fp32 -> bf16 in ws. 16384x256 threads.
__global__ void prep_x(const float4* __restrict__ x, ushort4* __restrict__ xb) {
  int i = blockIdx.x * 256 + threadIdx.x;
  float4 v = x[i];
  ushort4 o;
  o.x = f2bf(v.x); o.y = f2bf(v.y); o.z = f2bf(v.z); o.w = f2bf(v.w);
  xb[i] = o;
}

// ---- prep: 8-buffer rotation per dir. buf0 = f2bf(h0); bufs 1..7 = sentinel.
__global__ void prep_init(const float* __restrict__ h0f, const float* __restrict__ h0b,
                          unsigned short* __restrict__ hbufs) {
  int i = blockIdx.x * 256 + threadIdx.x;          // < 524288
  int dir = i >> 18;
  int rem = i & 262143;
  int buf = rem >> 15;
  int idx = rem & 32767;
  const float* src = dir ? h0b : h0f;
  hbufs[i] = (buf == 0) ? f2bf(src[idx]) : (unsigned short)0x7FC0;
}

// ---- persistent bidirectional LSTM. grid=128 (64 WGs/dir), block=256.
// SELF-SIGNALING + INCREMENTAL CONSUMPTION + PROBE POLLING:
//   h^(s) in buf[s&7] (per dir); chunk = (batch row, 8 units) as ONE dwordx4;
//   bf16 NaN 0x7FC0 = "empty" (unreachable, |h|<=1). Consumers poll the data.
//   Full verify = all 4 dwords non-sentinel (torn-safe under ANY store
//   granularity: unwritten dwords still show the clear's sentinel).
//   When many chunks are missing, poll with 4B dword-probes (1/4 NoC bytes);
//   a probed-ready chunk gets its full 16B load next round, then the normal
//   verify. When <=6 missing, reload fulls directly (no probe latency on the
//   straggler tail). MFMAs of newly-verified chunks overlap the next round's
//   load flight.
// Reuse safety (wave-local ordering only, unchanged from R6): chunk cleared
//   to sentinel by ITS OWN FUTURE WRITER at step s for buf[(s+2)&7] (holds
//   retired h^(s-6)); the clear drains at this step's first poll vmcnt(0),
//   before this wave's h^(s+1) store issues, so a non-sentinel dword is
//   always current-generation. Probes are hints only; verify is authority.
// Deadlock-free: the only blocking point is the data poll; every miss chunk
//   gets a probe or full load every round; producers store unconditionally;
//   128 blocks @ (256,1) capacity-co-resident.
__global__ __launch_bounds__(256, 1) void lstm_coop(
    const unsigned short* __restrict__ xbf,
    unsigned short* __restrict__ hbufs,
    const float* __restrict__ Wih_f, const float* __restrict__ Whh_f,
    const float* __restrict__ bih_f, const float* __restrict__ bhh_f,
    const float* __restrict__ c0_f,
    const float* __restrict__ Wih_b, const float* __restrict__ Whh_b,
    const float* __restrict__ bih_b, const float* __restrict__ bhh_b,
    const float* __restrict__ c0_b,
    float* __restrict__ out) {
  const int tid = threadIdx.x;
  const int wave = tid >> 6;
  const int lane = tid & 63;
  const int quad = lane >> 4;
  const int lm = lane & 15;

  const int wg = blockIdx.x;
  const int dir = wg >> 6;       // 0 = forward, 1 = backward
  const int jw = wg & 63;        // hidden-slice index
  const int hb = jw * 8;         // first hidden unit owned

  const float* Wih = dir ? Wih_b : Wih_f;
  const float* Whh = dir ? Whh_b : Whh_f;
  const float* bih = dir ? bih_b : bih_f;
  const float* bhh = dir ? bhh_b : bhh_f;
  const float* c0  = dir ? c0_b  : c0_f;

  // ---- weight fragments: 32 gate rows x K=512, both matrices, in registers ----
  short8 wx[2][16], wh[2][16];
#pragma unroll
  for (int nt = 0; nt < 2; ++nt) {
    int nl = nt * 16 + lm;
    int row = (nl >> 3) * 512 + hb + (nl & 7);
#pragma unroll
    for (int kk = 0; kk < 16; ++kk) {
      int k = kk * 32 + quad * 8;
      wx[nt][kk] = loadWfrag(Wih + (size_t)row * 512 + k);
      wh[nt][kk] = loadWfrag(Whh + (size_t)row * 512 + k);
    }
  }

  // epilogue ownership: lane (quad,lm): unit u=lm&7 (lm>=8 duplicates),
  // batch rows b0..b0+3 of this wave's 16.
  const int u = lm & 7;
  float bsum[4];
#pragma unroll
  for (int g = 0; g < 4; ++g)
    bsum[g] = bih[g * 512 + hb + u] + bhh[g * 512 + hb + u];

  const int b0 = wave * 16 + quad * 4;
  float creg[4], hlast[4];
#pragma unroll
  for (int r = 0; r < 4; ++r) {
    creg[r] = c0[(size_t)(b0 + r) * 512 + hb + u];
    hlast[r] = 0.f;
  }

  // ---- pointers ----
  char* hdir = (char*)hbufs + (size_t)dir * 8 * 65536;     // 8 rotating 64KB buffers
  const int arow = wave * 16 + lm;                          // A-fragment batch row
  const char* hload_lane = hdir + (size_t)arow * 1024 + quad * 16;
  // producer store row: r0 covered by lanes lm={0,2,4,6} per quad
  const int r0 = (lm & 2) | ((lm & 4) >> 2);
  char* hstore_lane = hdir + (size_t)(wave * 16 + quad * 4 + r0) * 1024 + jw * 16;
  const bool wr = (lm < 8) && ((lm & 1) == 0);
  const char* xb_lane = (const char*)xbf + (size_t)arow * 1024 + quad * 16;

  const i32x4 sent4 = {SENT32, SENT32, SENT32, SENT32};

  // ---- initial x prefetch (drained before the loop) ----
  short8 xf[16];
  {
    const char* xsrc = xb_lane + (size_t)(dir ? 511 : 0) * 65536;
    LDX_ALL();
  }
  asm volatile("s_waitcnt vmcnt(0)" ::: "memory");

  for (int s = 0; s < 512; ++s) {
    const int t = dir ? (511 - s) : s;

    // A: clear my future chunks in buf[(s+2)&7] (holds retired h^(s-6))
    if (wr) st16(hstore_lane + (size_t)((s + 2) & 7) * 65536, sent4);

    // B: issue the full h^(s) round IMMEDIATELY (before waiting for xf)
    const char* hsrc = hload_lane + (size_t)(s & 7) * 65536;
    short8 hf[16];
    LDH_ALL();

    // wait for xf only: allow the 17 just-issued ops (A + 16 h loads);
    // everything older (prev-iter h store, out stores, x prefetch) drains.
    asm volatile("s_waitcnt vmcnt(17)" ::: "memory");
    __builtin_amdgcn_sched_barrier(0);

    // x MFMAs (no h dependency; run while the h round is in flight)
    f32x4 acc0 = {0.f, 0.f, 0.f, 0.f};
    f32x4 acc1 = {0.f, 0.f, 0.f, 0.f};
#pragma unroll
    for (int kk = 0; kk < 16; ++kk) {
      acc0 = MFMA(xf[kk], wx[0][kk], acc0);
      acc1 = MFMA(xf[kk], wx[1][kk], acc1);
    }

    // C: probe/verify/consume poll. infl = chunks with full load in flight.
    {
      unsigned done = 0, infl = 0xFFFFu;
      int pr[16];
      while (true) {
        asm volatile("s_waitcnt vmcnt(0)" ::: "memory");  // round 1 also drains clear A
        __builtin_amdgcn_sched_barrier(0);
        // verify in-flight full loads (all 4 dwords non-sentinel, wave-uniform)
        unsigned newly = 0;
#pragma unroll
        for (int kk = 0; kk < 16; ++kk)
          if ((infl >> kk) & 1u) {
            i32x4 w = __builtin_bit_cast(i32x4, hf[kk]);
            int ok = (w[0] != SENT32) & (w[1] != SENT32) &
                     (w[2] != SENT32) & (w[3] != SENT32);
            if (__all(ok)) newly |= 1u << kk;
          }
        done |= newly;
        if (done == 0xFFFFu) { CONSUME(newly); break; }
        unsigned miss = 0xFFFFu & ~done;
        // probe results from last round (chunks that had probes, not fulls)
        unsigned probed = miss & ~infl;
        unsigned readym = 0;
#pragma unroll
        for (int kk = 0; kk < 16; ++kk)
          if ((probed >> kk) & 1u) {
            if (__all(pr[kk] != SENT32)) readym |= 1u << kk;
          }
        unsigned refull, reprobe;
        if (__builtin_popcount(miss) <= 6) { refull = miss; reprobe = 0; }
        else { refull = readym; reprobe = miss & ~readym; }
        // issue next round's loads first (flight overlaps the MFMAs below)
        LDH_MASK(refull);
        PRB_MASK(reprobe);
        infl = refull;
        CONSUME(newly);
      }
    }

    // E: gate exchange within lane pair (lm ^ 8); D col=lane&15, row=quad*4+r
    float hv[4];
#pragma unroll
    for (int r = 0; r < 4; ++r) {
      float p0 = __shfl_xor(acc0[r], 8, 64);
      float p1 = __shfl_xor(acc1[r], 8, 64);
      float gi  = (lm < 8 ? acc0[r] : p0) + bsum[0];
      float gfr = (lm < 8 ? p0 : acc0[r]) + bsum[1];
      float gg  = (lm < 8 ? acc1[r] : p1) + bsum[2];
      float go  = (lm < 8 ? p1 : acc1[r]) + bsum[3];
      float cn = sigm(gfr) * creg[r] + sigm(gi) * tanh_fast(gg);
      creg[r] = cn;
      hv[r] = sigm(go) * tanh_fast(cn);
      hlast[r] = hv[r];
    }
    // float unit-pair partners (also used for fp32 out stores)
    float q0 = __shfl_xor(hv[0], 1, 64), q1 = __shfl_xor(hv[1], 1, 64);
    float q2 = __shfl_xor(hv[2], 1, 64), q3 = __shfl_xor(hv[3], 1, 64);

    // pack tree: gather one full (row, 8-unit) 16B chunk per even lane.
    {
      const int ue = ((lm & 1) == 0);
      int V0 = ue ? ((int)f2bf(hv[0]) | ((int)f2bf(q0) << 16))
                  : ((int)f2bf(q0) | ((int)f2bf(hv[0]) << 16));
      int V1 = ue ? ((int)f2bf(hv[1]) | ((int)f2bf(q1) << 16))
                  : ((int)f2bf(q1) | ((int)f2bf(hv[1]) << 16));
      int V2 = ue ? ((int)f2bf(hv[2]) | ((int)f2bf(q2) << 16))
                  : ((int)f2bf(q2) | ((int)f2bf(hv[2]) << 16));
      int V3 = ue ? ((int)f2bf(hv[3]) | ((int)f2bf(q3) << 16))
                  : ((int)f2bf(q3) | ((int)f2bf(hv[3]) << 16));
      int P0 = __shfl_xor(V0, 2, 64), P1 = __shfl_xor(V1, 2, 64);
      int P2 = __shfl_xor(V2, 2, 64), P3 = __shfl_xor(V3, 2, 64);
      int X0 = ((lm & 2) == 0) ? V0 : P2;
      int X1 = ((lm & 2) == 0) ? P0 : V2;
      int X2 = ((lm & 2) == 0) ? V1 : P3;
      int X3 = ((lm & 2) == 0) ? P1 : V3;
      int Y0 = __shfl_xor(X0, 4, 64), Y1 = __shfl_xor(X1, 4, 64);
      int Y2 = __shfl_xor(X2, 4, 64), Y3 = __shfl_xor(X3, 4, 64);
      i32x4 Z;
      if ((lm & 4) == 0) { Z[0] = X0; Z[1] = X1; Z[2] = Y0; Z[3] = Y1; }
      else               { Z[0] = Y2; Z[1] = Y3; Z[2] = X2; Z[3] = X3; }
      // F: h^(s+1) chunk store -- data IS the signal (issued first in the tail)
      if (wr) st16(hstore_lane + (size_t)((s + 1) & 7) * 65536, Z);
    }

    // H: out stores (plain cached fp32; off the critical path)
    if (lm < 8) {
      const int sel = lm & 1;
      float2 vA = sel ? make_float2(q2, hv[2]) : make_float2(hv[0], q0);
      float2 vB = sel ? make_float2(q3, hv[3]) : make_float2(hv[1], q1);
      float* ob = out + (size_t)t * 65536 + dir * 512 + hb + (lm & ~1);
      *(float2*)(ob + (size_t)(b0 + 2 * sel) * 1024) = vA;
      *(float2*)(ob + (size_t)(b0 + 2 * sel + 1) * 1024) = vB;
    }

    // G: x prefetch for next step (16 loads; drained by next iter's vmcnt(17))
    {
      int sn = s + 1 < 512 ? s + 1 : 511;
      int tn = dir ? (511 - sn) : sn;
      const char* xsrc = xb_lane + (size_t)tn * 65536;
      LDX_ALL();
    }
  }

  // ---- final hT, cT ----
  if (lm < 8) {
    float* obase = out + 33554432 + dir * 65536;
#pragma unroll
    for (int r = 0; r < 4; ++r) {
      obase[(size_t)(b0 + r) * 512 + hb + u] = hlast[r];
      obase[32768 + (size_t)(b0 + r) * 512 + hb + u] = creg[r];
    }
  }
}

extern "C" void kernel_launch(void* const* d_in, const int* in_sizes, int n_in,
                              void* d_out, int out_size, void* d_ws, size_t ws_size,
                              hipStream_t stream) {
  (void)in_sizes; (void)n_in; (void)out_size; (void)ws_size;

  const float* X     = (const float*)d_in[0];
  const float* h0_f  = (const float*)d_in[1];
  const float* c0_f  = (const float*)d_in[2];
  const float* h0_b  = (const float*)d_in[3];
  const float* c0_b  = (const float*)d_in[4];
  const float* Wih_f = (const float*)d_in[5];
  const float* Whh_f = (const float*)d_in[6];
  const float* bih_f = (const float*)d_in[7];
  const float* bhh_f = (const float*)d_in[8];
  const float* Wih_b = (const float*)d_in[9];
  const float* Whh_b = (const float*)d_in[10];
  const float* bih_b = (const float*)d_in[11];
  const float* bhh_b = (const float*)d_in[12];
  float* out = (float*)d_out;

  unsigned short* xbf   = (unsigned short*)d_ws;                      // 33,554,432 B
  unsigned short* hbufs = (unsigned short*)((char*)d_ws + 33554432);  //  1,048,576 B (2 dirs x 8 x 64KB)

  prep_x<<<16384, 256, 0, stream>>>((const float4*)X, (ushort4*)xbf);
  prep_init<<<2048, 256, 0, stream>>>(h0_f, h0_b, hbufs);

  lstm_coop<<<dim3(128), dim3(256), 0, stream>>>(
      xbf, hbufs,
      Wih_f, Whh_f, bih_f, bhh_f, c0_f,
      Wih_b, Whh_b, bih_b, bhh_b, c0_b,
      out);
}